// Round 1
// baseline (4395.692 us; speedup 1.0000x reference)
//
#include <hip/hip_runtime.h>
#include <hip/hip_bf16.h>
#include <math.h>

// GCN_with_CRF: the group_softmax over singleton groups (seg = arange(n)) is
// identically 1.0, so the whole CRF scatter collapses to h = 0.9*relu(gcn1)+0.1.
// Pipeline: gemm1 -> deg/dinv/coeff -> init1+scatter1 -> gemm2(fused relu/affine)
//           -> init2+scatter2 (into d_out) -> log_softmax in-place.

#define F_IN  256
#define F_HID 128
#define F_OUT 64

__device__ __forceinline__ void atomAddF(float* p, float v) {
  unsafeAtomicAdd(p, v);  // hardware global_atomic_add_f32 on gfx950
}

// ---------------- degree / dinv / per-edge coeff ----------------
__global__ void k_count_deg(const int* __restrict__ dstv, int E, int* __restrict__ deg) {
  int i = blockIdx.x * blockDim.x + threadIdx.x;
  if (i < E) atomicAdd(&deg[dstv[i]], 1);
}

__global__ void k_dinv(const int* __restrict__ deg, float* __restrict__ dinv, int N) {
  int i = blockIdx.x * blockDim.x + threadIdx.x;
  if (i < N) dinv[i] = rsqrtf((float)deg[i] + 1.0f);
}

__global__ void k_coeff(const int* __restrict__ srcv, const int* __restrict__ dstv,
                        const float* __restrict__ dinv, float* __restrict__ coeff, int E) {
  int i = blockIdx.x * blockDim.x + threadIdx.x;
  if (i < E) coeff[i] = dinv[srcv[i]] * dinv[dstv[i]];
}

// ---------------- GEMM1: h0 = x @ W1  (M x 256) @ (256 x 128), f32 ----------------
// BM=64, BN=128(full), BK=16; 256 threads; thread tile 4x8 (two float4 col groups).
__global__ __launch_bounds__(256) void k_gemm1(const float* __restrict__ X,
                                               const float* __restrict__ W,
                                               float* __restrict__ H, int M) {
  __shared__ float As[16][68];    // [k][m] transposed, padded
  __shared__ float Bs[16][132];   // [k][n], padded
  const int brow = blockIdx.x * 64;
  const int tid = threadIdx.x;
  const int tx = tid & 15;        // col group: cols tx*4 and 64+tx*4
  const int ty = tid >> 4;        // row group: rows ty*4..+3
  const int ar = tid >> 2;        // A-load row 0..63
  const int ac = (tid & 3) * 4;   // A-load k chunk
  const int br = tid >> 4;        // B-load k row 0..15
  const int bc = (tid & 15) * 8;  // B-load col chunk

  int arow_g = brow + ar; if (arow_g >= M) arow_g = M - 1;  // clamp (stores guarded)
  float acc[4][8] = {};

  for (int k0 = 0; k0 < F_IN; k0 += 16) {
    const float4 av  = *(const float4*)&X[(size_t)arow_g * F_IN + k0 + ac];
    const float4 bv0 = *(const float4*)&W[(size_t)(k0 + br) * F_HID + bc];
    const float4 bv1 = *(const float4*)&W[(size_t)(k0 + br) * F_HID + bc + 4];
    __syncthreads();
    As[ac + 0][ar] = av.x; As[ac + 1][ar] = av.y;
    As[ac + 2][ar] = av.z; As[ac + 3][ar] = av.w;
    *(float4*)&Bs[br][bc]     = bv0;
    *(float4*)&Bs[br][bc + 4] = bv1;
    __syncthreads();
#pragma unroll
    for (int kk = 0; kk < 16; ++kk) {
      const float4 a  = *(const float4*)&As[kk][ty * 4];
      const float4 b0 = *(const float4*)&Bs[kk][tx * 4];
      const float4 b1 = *(const float4*)&Bs[kk][64 + tx * 4];
      const float aa[4] = {a.x, a.y, a.z, a.w};
      const float bb[8] = {b0.x, b0.y, b0.z, b0.w, b1.x, b1.y, b1.z, b1.w};
#pragma unroll
      for (int i = 0; i < 4; ++i)
#pragma unroll
        for (int j = 0; j < 8; ++j) acc[i][j] += aa[i] * bb[j];
    }
  }
#pragma unroll
  for (int i = 0; i < 4; ++i) {
    const int r = brow + ty * 4 + i;
    if (r < M) {
      float4 o0 = {acc[i][0], acc[i][1], acc[i][2], acc[i][3]};
      float4 o1 = {acc[i][4], acc[i][5], acc[i][6], acc[i][7]};
      *(float4*)&H[(size_t)r * F_HID + tx * 4]      = o0;
      *(float4*)&H[(size_t)r * F_HID + 64 + tx * 4] = o1;
    }
  }
}

// ---------------- GEMM2: h2 = (0.9*relu(agg1)+0.1) @ W2  (M x 128)@(128 x 64) ----------------
// W2 (32KB) fully resident in LDS; BM=64, BK=16; thread tile 4x4.
__global__ __launch_bounds__(256) void k_gemm2(const float* __restrict__ AGG1,
                                               const float* __restrict__ W2,
                                               float* __restrict__ H2, int M) {
  __shared__ float As[16][68];
  __shared__ float Bs[128][64];
  const int brow = blockIdx.x * 64;
  const int tid = threadIdx.x;
  const int tx = tid & 15;        // cols tx*4..+3
  const int ty = tid >> 4;        // rows ty*4..+3
  const int ar = tid >> 2;
  const int ac = (tid & 3) * 4;

#pragma unroll
  for (int l = 0; l < 8; ++l) {   // load all of W2: 8192 floats
    const int idx = (l * 256 + tid) * 4;
    *(float4*)&((float*)Bs)[idx] = *(const float4*)&W2[idx];
  }

  int arow_g = brow + ar; if (arow_g >= M) arow_g = M - 1;
  float acc[4][4] = {};

  for (int k0 = 0; k0 < F_HID; k0 += 16) {
    float4 av = *(const float4*)&AGG1[(size_t)arow_g * F_HID + k0 + ac];
    av.x = 0.9f * fmaxf(av.x, 0.0f) + 0.1f;   // fused relu + CRF-mix
    av.y = 0.9f * fmaxf(av.y, 0.0f) + 0.1f;
    av.z = 0.9f * fmaxf(av.z, 0.0f) + 0.1f;
    av.w = 0.9f * fmaxf(av.w, 0.0f) + 0.1f;
    __syncthreads();              // also covers the one-time W2 load on iter 0
    As[ac + 0][ar] = av.x; As[ac + 1][ar] = av.y;
    As[ac + 2][ar] = av.z; As[ac + 3][ar] = av.w;
    __syncthreads();
#pragma unroll
    for (int kk = 0; kk < 16; ++kk) {
      const float4 a = *(const float4*)&As[kk][ty * 4];
      const float4 b = *(const float4*)&Bs[k0 + kk][tx * 4];
      const float aa[4] = {a.x, a.y, a.z, a.w};
      const float bb[4] = {b.x, b.y, b.z, b.w};
#pragma unroll
      for (int i = 0; i < 4; ++i)
#pragma unroll
        for (int j = 0; j < 4; ++j) acc[i][j] += aa[i] * bb[j];
    }
  }
#pragma unroll
  for (int i = 0; i < 4; ++i) {
    const int r = brow + ty * 4 + i;
    if (r < M) {
      float4 o = {acc[i][0], acc[i][1], acc[i][2], acc[i][3]};
      *(float4*)&H2[(size_t)r * F_OUT + tx * 4] = o;
    }
  }
}

// ---------------- init: out = dinv^2 * feat + bias (self-loop term) ----------------
template <int SHIFT>  // feats = 4<<SHIFT
__global__ void k_init(const float* __restrict__ feat, const float* __restrict__ dinv,
                       const float* __restrict__ bias, float* __restrict__ outv, long total) {
  const long i = (long)blockIdx.x * blockDim.x + threadIdx.x;
  if (i >= total) return;
  const int node = (int)(i >> SHIFT);
  const int c4 = ((int)i & ((1 << SHIFT) - 1)) * 4;
  const int F = 4 << SHIFT;
  const float dv = dinv[node];
  const float d2 = dv * dv;
  const float4 h = *(const float4*)&feat[(size_t)node * F + c4];
  const float4 b = *(const float4*)&bias[c4];
  float4 o = {d2 * h.x + b.x, d2 * h.y + b.y, d2 * h.z + b.z, d2 * h.w + b.w};
  *(float4*)&outv[(size_t)node * F + c4] = o;
}

// ---------------- scatter: outv[dst] += coeff[e] * feat[src], float4 per thread ----------------
template <int SHIFT>  // feats = 4<<SHIFT
__global__ void k_scatter(const int* __restrict__ srcv, const int* __restrict__ dstv,
                          const float* __restrict__ coeff, const float* __restrict__ feat,
                          float* __restrict__ outv, long total) {
  const long i = (long)blockIdx.x * blockDim.x + threadIdx.x;
  if (i >= total) return;
  const int e = (int)(i >> SHIFT);
  const int c4 = ((int)i & ((1 << SHIFT) - 1)) * 4;
  const int F = 4 << SHIFT;
  const float cf = coeff[e];
  const int s = srcv[e];
  const int d = dstv[e];
  const float4 h = *(const float4*)&feat[(size_t)s * F + c4];
  float* o = &outv[(size_t)d * F + c4];
  atomAddF(o + 0, cf * h.x);
  atomAddF(o + 1, cf * h.y);
  atomAddF(o + 2, cf * h.z);
  atomAddF(o + 3, cf * h.w);
}

// ---------------- in-place log_softmax over 64 cols; one wave per row ----------------
__global__ void k_logsoftmax(float* __restrict__ outv, int N) {
  const int wave = threadIdx.x >> 6;
  const int lane = threadIdx.x & 63;
  const int row = blockIdx.x * 4 + wave;
  if (row >= N) return;
  const float v = outv[(size_t)row * 64 + lane];
  float m = v;
#pragma unroll
  for (int off = 32; off; off >>= 1) m = fmaxf(m, __shfl_xor(m, off));
  const float ex = expf(v - m);
  float s = ex;
#pragma unroll
  for (int off = 32; off; off >>= 1) s += __shfl_xor(s, off);
  outv[(size_t)row * 64 + lane] = v - m - logf(s);
}

// ---------------- launch ----------------
extern "C" void kernel_launch(void* const* d_in, const int* in_sizes, int n_in,
                              void* d_out, int out_size, void* d_ws, size_t ws_size,
                              hipStream_t stream) {
  const float* x  = (const float*)d_in[0];
  const int*   ei = (const int*)d_in[1];
  // d_in[2] = edge_weight: unused (CRF softmax over singleton groups == 1)
  const float* W1 = (const float*)d_in[3];
  const float* b1 = (const float*)d_in[4];
  const float* W2 = (const float*)d_in[5];
  const float* b2 = (const float*)d_in[6];

  const int N = in_sizes[0] / F_IN;
  const int E = in_sizes[1] / 2;
  const int* srcv = ei;
  const int* dstv = ei + E;

  // workspace layout (floats), 256-element aligned
  float* ws = (float*)d_ws;
  const size_t Na = ((size_t)N + 255) & ~(size_t)255;
  const size_t Ea = ((size_t)E + 255) & ~(size_t)255;
  float* dinv  = ws;                      // N
  int*   deg   = (int*)(ws + Na);         // N
  float* coeff = ws + 2 * Na;             // E
  float* h0    = coeff + Ea;              // N*128
  float* agg1  = h0 + (size_t)N * F_HID;  // N*128
  float* h2    = h0;                      // alias: h0 dead once scatter1/init1 done
  float* outp  = (float*)d_out;           // N*64, doubles as agg2 accumulator

  hipMemsetAsync(deg, 0, (size_t)N * sizeof(int), stream);
  k_count_deg<<<(E + 255) / 256, 256, 0, stream>>>(dstv, E, deg);
  k_dinv<<<(N + 255) / 256, 256, 0, stream>>>(deg, dinv, N);
  k_coeff<<<(E + 255) / 256, 256, 0, stream>>>(srcv, dstv, dinv, coeff, E);

  k_gemm1<<<(N + 63) / 64, 256, 0, stream>>>(x, W1, h0, N);

  { // layer-1 aggregation: agg1 = dinv^2*h0 + b1 + scatter
    const long t_init = (long)N * (F_HID / 4);
    const long t_scat = (long)E * (F_HID / 4);
    k_init<5><<<(int)((t_init + 255) / 256), 256, 0, stream>>>(h0, dinv, b1, agg1, t_init);
    k_scatter<5><<<(int)((t_scat + 255) / 256), 256, 0, stream>>>(srcv, dstv, coeff, h0, agg1, t_scat);
  }

  k_gemm2<<<(N + 63) / 64, 256, 0, stream>>>(agg1, W2, h2, N);

  { // layer-2 aggregation directly into d_out
    const long t_init = (long)N * (F_OUT / 4);
    const long t_scat = (long)E * (F_OUT / 4);
    k_init<4><<<(int)((t_init + 255) / 256), 256, 0, stream>>>(h2, dinv, b2, outp, t_init);
    k_scatter<4><<<(int)((t_scat + 255) / 256), 256, 0, stream>>>(srcv, dstv, coeff, h2, outp, t_scat);
  }

  k_logsoftmax<<<(N + 3) / 4, 256, 0, stream>>>(outp, N);
}

// Round 2
// 650.159 us; speedup vs baseline: 6.7609x; 6.7609x over previous
//
#include <hip/hip_runtime.h>
#include <hip/hip_bf16.h>
#include <math.h>

// GCN_with_CRF: group_softmax over singleton groups (seg = arange(n)) == 1.0,
// so the CRF collapses to h = 0.9*relu(gcn1) + 0.1 and edge_weight is unused.
// Round 2: replace float-atomic scatter (204M+102M atomics, 62x write
// amplification, 4.0 ms) with device-built CSR (by dst) + one-wave-per-node
// register gather. init/bias/logsoftmax fused into the gathers.

#define F_IN  256
#define F_HID 128
#define F_OUT 64

// ---------------- degree / dinv ----------------
__global__ void k_count_deg(const int* __restrict__ dstv, int E, int* __restrict__ deg) {
  int i = blockIdx.x * blockDim.x + threadIdx.x;
  if (i < E) atomicAdd(&deg[dstv[i]], 1);
}

__global__ void k_dinv(const int* __restrict__ deg, float* __restrict__ dinv, int N) {
  int i = blockIdx.x * blockDim.x + threadIdx.x;
  if (i < N) dinv[i] = rsqrtf((float)deg[i] + 1.0f);
}

// ---------------- prefix scan: deg -> rowptr (exclusive) ----------------
__global__ __launch_bounds__(1024) void k_chunk_sum(const int* __restrict__ deg,
                                                    int* __restrict__ chunkSum, int N) {
  __shared__ int sm[16];
  const int i = blockIdx.x * 1024 + threadIdx.x;
  int v = (i < N) ? deg[i] : 0;
#pragma unroll
  for (int off = 32; off; off >>= 1) v += __shfl_down(v, off);
  if ((threadIdx.x & 63) == 0) sm[threadIdx.x >> 6] = v;
  __syncthreads();
  if (threadIdx.x == 0) {
    int x = 0;
#pragma unroll
    for (int k = 0; k < 16; ++k) x += sm[k];
    chunkSum[blockIdx.x] = x;
  }
}

__global__ __launch_bounds__(128) void k_scan_off(const int* __restrict__ chunkSum,
                                                  int* __restrict__ chunkOff, int B,
                                                  int* __restrict__ rowptr, int N, int E) {
  __shared__ int sm[128];
  const int t = threadIdx.x;
  const int v = (t < B) ? chunkSum[t] : 0;
  sm[t] = v;
  __syncthreads();
  int run = v;
  for (int off = 1; off < 128; off <<= 1) {
    const int add = (t >= off) ? sm[t - off] : 0;
    __syncthreads();
    run += add;
    sm[t] = run;
    __syncthreads();
  }
  if (t < B) chunkOff[t] = run - v;  // exclusive chunk offsets
  if (t == 0) rowptr[N] = E;
}

__global__ __launch_bounds__(1024) void k_scan_apply(const int* __restrict__ deg,
                                                     const int* __restrict__ chunkOff,
                                                     int* __restrict__ rowptr, int N) {
  __shared__ int sm[1024];
  const int t = threadIdx.x;
  const int i = blockIdx.x * 1024 + t;
  const int v = (i < N) ? deg[i] : 0;
  sm[t] = v;
  __syncthreads();
  int run = v;
  for (int off = 1; off < 1024; off <<= 1) {
    const int add = (t >= off) ? sm[t - off] : 0;
    __syncthreads();
    run += add;
    sm[t] = run;
    __syncthreads();
  }
  if (i < N) rowptr[i] = chunkOff[blockIdx.x] + run - v;  // exclusive
}

// ---------------- CSR fill: csr_src[pos] = src for edges grouped by dst ----------------
__global__ void k_fill(const int* __restrict__ srcv, const int* __restrict__ dstv,
                       const int* __restrict__ rowptr, int* __restrict__ fill,
                       int* __restrict__ csr_src, int E) {
  int e = blockIdx.x * blockDim.x + threadIdx.x;
  if (e < E) {
    const int d = dstv[e];
    const int pos = rowptr[d] + atomicAdd(&fill[d], 1);
    csr_src[pos] = srcv[e];
  }
}

// ---------------- GEMM1: h0 = x @ W1  (M x 256) @ (256 x 128), f32 ----------------
__global__ __launch_bounds__(256) void k_gemm1(const float* __restrict__ X,
                                               const float* __restrict__ W,
                                               float* __restrict__ H, int M) {
  __shared__ float As[16][68];    // [k][m] transposed, padded
  __shared__ float Bs[16][132];   // [k][n], padded
  const int brow = blockIdx.x * 64;
  const int tid = threadIdx.x;
  const int tx = tid & 15;
  const int ty = tid >> 4;
  const int ar = tid >> 2;
  const int ac = (tid & 3) * 4;
  const int br = tid >> 4;
  const int bc = (tid & 15) * 8;

  int arow_g = brow + ar; if (arow_g >= M) arow_g = M - 1;
  float acc[4][8] = {};

  for (int k0 = 0; k0 < F_IN; k0 += 16) {
    const float4 av  = *(const float4*)&X[(size_t)arow_g * F_IN + k0 + ac];
    const float4 bv0 = *(const float4*)&W[(size_t)(k0 + br) * F_HID + bc];
    const float4 bv1 = *(const float4*)&W[(size_t)(k0 + br) * F_HID + bc + 4];
    __syncthreads();
    As[ac + 0][ar] = av.x; As[ac + 1][ar] = av.y;
    As[ac + 2][ar] = av.z; As[ac + 3][ar] = av.w;
    *(float4*)&Bs[br][bc]     = bv0;
    *(float4*)&Bs[br][bc + 4] = bv1;
    __syncthreads();
#pragma unroll
    for (int kk = 0; kk < 16; ++kk) {
      const float4 a  = *(const float4*)&As[kk][ty * 4];
      const float4 b0 = *(const float4*)&Bs[kk][tx * 4];
      const float4 b1 = *(const float4*)&Bs[kk][64 + tx * 4];
      const float aa[4] = {a.x, a.y, a.z, a.w};
      const float bb[8] = {b0.x, b0.y, b0.z, b0.w, b1.x, b1.y, b1.z, b1.w};
#pragma unroll
      for (int i = 0; i < 4; ++i)
#pragma unroll
        for (int j = 0; j < 8; ++j) acc[i][j] += aa[i] * bb[j];
    }
  }
#pragma unroll
  for (int i = 0; i < 4; ++i) {
    const int r = brow + ty * 4 + i;
    if (r < M) {
      float4 o0 = {acc[i][0], acc[i][1], acc[i][2], acc[i][3]};
      float4 o1 = {acc[i][4], acc[i][5], acc[i][6], acc[i][7]};
      *(float4*)&H[(size_t)r * F_HID + tx * 4]      = o0;
      *(float4*)&H[(size_t)r * F_HID + 64 + tx * 4] = o1;
    }
  }
}

// ---------------- GEMM2: h2 = (0.9*relu(agg1)+0.1) @ W2  (M x 128)@(128 x 64) ----------------
__global__ __launch_bounds__(256) void k_gemm2(const float* __restrict__ AGG1,
                                               const float* __restrict__ W2,
                                               float* __restrict__ H2, int M) {
  __shared__ float As[16][68];
  __shared__ float Bs[128][64];
  const int brow = blockIdx.x * 64;
  const int tid = threadIdx.x;
  const int tx = tid & 15;
  const int ty = tid >> 4;
  const int ar = tid >> 2;
  const int ac = (tid & 3) * 4;

#pragma unroll
  for (int l = 0; l < 8; ++l) {
    const int idx = (l * 256 + tid) * 4;
    *(float4*)&((float*)Bs)[idx] = *(const float4*)&W2[idx];
  }

  int arow_g = brow + ar; if (arow_g >= M) arow_g = M - 1;
  float acc[4][4] = {};

  for (int k0 = 0; k0 < F_HID; k0 += 16) {
    float4 av = *(const float4*)&AGG1[(size_t)arow_g * F_HID + k0 + ac];
    av.x = 0.9f * fmaxf(av.x, 0.0f) + 0.1f;   // fused relu + CRF-mix
    av.y = 0.9f * fmaxf(av.y, 0.0f) + 0.1f;
    av.z = 0.9f * fmaxf(av.z, 0.0f) + 0.1f;
    av.w = 0.9f * fmaxf(av.w, 0.0f) + 0.1f;
    __syncthreads();
    As[ac + 0][ar] = av.x; As[ac + 1][ar] = av.y;
    As[ac + 2][ar] = av.z; As[ac + 3][ar] = av.w;
    __syncthreads();
#pragma unroll
    for (int kk = 0; kk < 16; ++kk) {
      const float4 a = *(const float4*)&As[kk][ty * 4];
      const float4 b = *(const float4*)&Bs[k0 + kk][tx * 4];
      const float aa[4] = {a.x, a.y, a.z, a.w};
      const float bb[4] = {b.x, b.y, b.z, b.w};
#pragma unroll
      for (int i = 0; i < 4; ++i)
#pragma unroll
        for (int j = 0; j < 4; ++j) acc[i][j] += aa[i] * bb[j];
    }
  }
#pragma unroll
  for (int i = 0; i < 4; ++i) {
    const int r = brow + ty * 4 + i;
    if (r < M) {
      float4 o = {acc[i][0], acc[i][1], acc[i][2], acc[i][3]};
      *(float4*)&H2[(size_t)r * F_OUT + tx * 4] = o;
    }
  }
}

// ---------------- layer-1 aggregation: one wave per node, lane owns 2 feats ----------------
__global__ __launch_bounds__(256) void k_gather1(const int* __restrict__ rowptr,
                                                 const int* __restrict__ csr_src,
                                                 const float* __restrict__ dinv,
                                                 const float* __restrict__ h0,
                                                 const float* __restrict__ b1,
                                                 float* __restrict__ agg1, int N) {
  const int node = (blockIdx.x << 2) + (threadIdx.x >> 6);
  if (node >= N) return;
  const int lane = threadIdx.x & 63;
  const int beg = rowptr[node];
  const int end = rowptr[node + 1];
  const float dv = dinv[node];
  const float2 hs = *(const float2*)&h0[(size_t)node * F_HID + lane * 2];
  const float2 bb = *(const float2*)&b1[lane * 2];
  float ax = dv * dv * hs.x + bb.x;
  float ay = dv * dv * hs.y + bb.y;
#pragma unroll 2
  for (int j = beg; j < end; ++j) {
    const int s = csr_src[j];                 // wave-uniform broadcast load
    const float w = dinv[s] * dv;
    const float2 hv = *(const float2*)&h0[(size_t)s * F_HID + lane * 2];
    ax += w * hv.x;
    ay += w * hv.y;
  }
  const float2 o = {ax, ay};
  *(float2*)&agg1[(size_t)node * F_HID + lane * 2] = o;
}

// ---------------- layer-2 aggregation + log_softmax: one wave per node ----------------
__global__ __launch_bounds__(256) void k_gather2_lsm(const int* __restrict__ rowptr,
                                                     const int* __restrict__ csr_src,
                                                     const float* __restrict__ dinv,
                                                     const float* __restrict__ h2,
                                                     const float* __restrict__ b2,
                                                     float* __restrict__ outv, int N) {
  const int node = (blockIdx.x << 2) + (threadIdx.x >> 6);
  if (node >= N) return;
  const int lane = threadIdx.x & 63;
  const int beg = rowptr[node];
  const int end = rowptr[node + 1];
  const float dv = dinv[node];
  float acc = dv * dv * h2[(size_t)node * F_OUT + lane] + b2[lane];
#pragma unroll 2
  for (int j = beg; j < end; ++j) {
    const int s = csr_src[j];
    acc += dinv[s] * dv * h2[(size_t)s * F_OUT + lane];
  }
  // fused log_softmax over the 64 lanes
  float m = acc;
#pragma unroll
  for (int off = 32; off; off >>= 1) m = fmaxf(m, __shfl_xor(m, off));
  const float ex = expf(acc - m);
  float s = ex;
#pragma unroll
  for (int off = 32; off; off >>= 1) s += __shfl_xor(s, off);
  outv[(size_t)node * F_OUT + lane] = acc - m - logf(s);
}

// ---------------- launch ----------------
extern "C" void kernel_launch(void* const* d_in, const int* in_sizes, int n_in,
                              void* d_out, int out_size, void* d_ws, size_t ws_size,
                              hipStream_t stream) {
  const float* x  = (const float*)d_in[0];
  const int*   ei = (const int*)d_in[1];
  // d_in[2] = edge_weight: unused (CRF softmax over singleton groups == 1)
  const float* W1 = (const float*)d_in[3];
  const float* b1 = (const float*)d_in[4];
  const float* W2 = (const float*)d_in[5];
  const float* b2 = (const float*)d_in[6];

  const int N = in_sizes[0] / F_IN;
  const int E = in_sizes[1] / 2;
  const int* srcv = ei;
  const int* dstv = ei + E;
  const int B = (N + 1023) / 1024;  // scan chunks

  // workspace layout (floats/ints), 256-element aligned
  float* ws = (float*)d_ws;
  const size_t Na = ((size_t)N + 256) & ~(size_t)255;  // room for rowptr[N]
  const size_t Ea = ((size_t)E + 255) & ~(size_t)255;
  float* dinv    = ws;                       // N
  int*   deg     = (int*)(ws + Na);          // N
  int*   fill    = (int*)(ws + 2 * Na);      // N
  int*   rowptr  = (int*)(ws + 3 * Na);      // N+1
  int*   chunkS  = (int*)(ws + 4 * Na);      // B (<=128)
  int*   chunkO  = chunkS + 128;             // B
  int*   csr_src = chunkO + 128;             // E
  float* h0      = (float*)(csr_src + Ea);   // N*128
  float* agg1    = h0 + (size_t)N * F_HID;   // N*128
  float* h2      = h0;                       // alias: h0 dead after gather1
  float* outp    = (float*)d_out;            // N*64

  // ---- CSR build ----
  hipMemsetAsync(deg, 0, (size_t)N * sizeof(int), stream);
  hipMemsetAsync(fill, 0, (size_t)N * sizeof(int), stream);
  k_count_deg<<<(E + 255) / 256, 256, 0, stream>>>(dstv, E, deg);
  k_dinv<<<(N + 255) / 256, 256, 0, stream>>>(deg, dinv, N);
  k_chunk_sum<<<B, 1024, 0, stream>>>(deg, chunkS, N);
  k_scan_off<<<1, 128, 0, stream>>>(chunkS, chunkO, B, rowptr, N, E);
  k_scan_apply<<<B, 1024, 0, stream>>>(deg, chunkO, rowptr, N);
  k_fill<<<(E + 255) / 256, 256, 0, stream>>>(srcv, dstv, rowptr, fill, csr_src, E);

  // ---- layer 1 ----
  k_gemm1<<<(N + 63) / 64, 256, 0, stream>>>(x, W1, h0, N);
  k_gather1<<<(N + 3) / 4, 256, 0, stream>>>(rowptr, csr_src, dinv, h0, b1, agg1, N);

  // ---- layer 2 (relu/affine fused in gemm2 A-load; lsm fused in gather2) ----
  k_gemm2<<<(N + 63) / 64, 256, 0, stream>>>(agg1, W2, h2, N);
  k_gather2_lsm<<<(N + 3) / 4, 256, 0, stream>>>(rowptr, csr_src, dinv, h2, b2, outp, N);
}

// Round 3
// 521.848 us; speedup vs baseline: 8.4233x; 1.2459x over previous
//
#include <hip/hip_runtime.h>
#include <math.h>

// GCN_with_CRF: group_softmax over singleton groups (seg = arange(n)) == 1.0,
// so the CRF collapses to h = 0.9*relu(gcn1) + 0.1 and edge_weight is unused.
// Round 3: bf16 intermediates (h0/agg1/h2) halve gather traffic; both GEMMs
// moved to mfma_f32_16x16x32_bf16 with LDS-resident swizzled B and A-fragments
// converted from global f32 in-register. Gathers accumulate f32.

#define F_IN  256
#define F_HID 128
#define F_OUT 64

typedef __attribute__((ext_vector_type(8))) __bf16 bf16x8;
typedef __attribute__((ext_vector_type(8))) short  s16x8;
typedef __attribute__((ext_vector_type(4))) float  f32x4;

__device__ __forceinline__ unsigned short f2bf(float f) {   // RNE f32->bf16 bits
  unsigned u = __builtin_bit_cast(unsigned, f);
  u += 0x7fffu + ((u >> 16) & 1u);
  return (unsigned short)(u >> 16);
}
__device__ __forceinline__ float bf2f(unsigned short s) {
  unsigned u = ((unsigned)s) << 16;
  return __builtin_bit_cast(float, u);
}

// ---------------- degree / dinv ----------------
__global__ void k_count_deg(const int* __restrict__ dstv, int E, int* __restrict__ deg) {
  int i = blockIdx.x * blockDim.x + threadIdx.x;
  if (i < E) atomicAdd(&deg[dstv[i]], 1);
}

__global__ void k_dinv(const int* __restrict__ deg, float* __restrict__ dinv, int N) {
  int i = blockIdx.x * blockDim.x + threadIdx.x;
  if (i < N) dinv[i] = rsqrtf((float)deg[i] + 1.0f);
}

// ---------------- prefix scan: deg -> rowptr (exclusive) ----------------
__global__ __launch_bounds__(1024) void k_chunk_sum(const int* __restrict__ deg,
                                                    int* __restrict__ chunkSum, int N) {
  __shared__ int sm[16];
  const int i = blockIdx.x * 1024 + threadIdx.x;
  int v = (i < N) ? deg[i] : 0;
#pragma unroll
  for (int off = 32; off; off >>= 1) v += __shfl_down(v, off);
  if ((threadIdx.x & 63) == 0) sm[threadIdx.x >> 6] = v;
  __syncthreads();
  if (threadIdx.x == 0) {
    int x = 0;
#pragma unroll
    for (int k = 0; k < 16; ++k) x += sm[k];
    chunkSum[blockIdx.x] = x;
  }
}

__global__ __launch_bounds__(128) void k_scan_off(const int* __restrict__ chunkSum,
                                                  int* __restrict__ chunkOff, int B,
                                                  int* __restrict__ rowptr, int N, int E) {
  __shared__ int sm[128];
  const int t = threadIdx.x;
  const int v = (t < B) ? chunkSum[t] : 0;
  sm[t] = v;
  __syncthreads();
  int run = v;
  for (int off = 1; off < 128; off <<= 1) {
    const int add = (t >= off) ? sm[t - off] : 0;
    __syncthreads();
    run += add;
    sm[t] = run;
    __syncthreads();
  }
  if (t < B) chunkOff[t] = run - v;
  if (t == 0) rowptr[N] = E;
}

__global__ __launch_bounds__(1024) void k_scan_apply(const int* __restrict__ deg,
                                                     const int* __restrict__ chunkOff,
                                                     int* __restrict__ rowptr, int N) {
  __shared__ int sm[1024];
  const int t = threadIdx.x;
  const int i = blockIdx.x * 1024 + t;
  const int v = (i < N) ? deg[i] : 0;
  sm[t] = v;
  __syncthreads();
  int run = v;
  for (int off = 1; off < 1024; off <<= 1) {
    const int add = (t >= off) ? sm[t - off] : 0;
    __syncthreads();
    run += add;
    sm[t] = run;
    __syncthreads();
  }
  if (i < N) rowptr[i] = chunkOff[blockIdx.x] + run - v;
}

// ---------------- CSR fill ----------------
__global__ void k_fill(const int* __restrict__ srcv, const int* __restrict__ dstv,
                       const int* __restrict__ rowptr, int* __restrict__ fill,
                       int* __restrict__ csr_src, int E) {
  int e = blockIdx.x * blockDim.x + threadIdx.x;
  if (e < E) {
    const int d = dstv[e];
    const int pos = rowptr[d] + atomicAdd(&fill[d], 1);
    csr_src[pos] = srcv[e];
  }
}

// ---------------- GEMM1 (MFMA): h0 = bf16(x @ W1), (Mx256)@(256x128) ----------------
// Block: 256 thr = 4 waves, M-tile 64 (16 rows/wave), full N=128 (8 frags/wave).
// W1 staged once to LDS as bf16 [n][k] with chunk XOR-swizzle (kc ^= n&7).
__global__ __launch_bounds__(256) void k_gemm1(const float* __restrict__ X,
                                               const float* __restrict__ W,
                                               unsigned short* __restrict__ H, int M) {
  __shared__ unsigned short Bs[128][256];  // 64 KB
  const int tid = threadIdx.x;
  { // stage: thread tid owns k=tid; rep r covers cols 4r..4r+3 (writes lane-contiguous k)
    const int kc = tid >> 3, kb = tid & 7;
#pragma unroll
    for (int r = 0; r < 32; ++r) {
      const float4 w = *(const float4*)&W[(size_t)tid * F_HID + r * 4];
      const float wv[4] = {w.x, w.y, w.z, w.w};
#pragma unroll
      for (int c = 0; c < 4; ++c) {
        const int n = r * 4 + c;
        Bs[n][((kc ^ (n & 7)) << 3) | kb] = f2bf(wv[c]);
      }
    }
  }
  const int lane = tid & 63;
  const int wv_ = tid >> 6;
  const int l15 = lane & 15;
  const int kgrp = (lane >> 4) << 3;           // 0,8,16,24
  const int rowA = blockIdx.x * 64 + wv_ * 16 + l15;
  const int rA = rowA < M ? rowA : M - 1;
  const float* xp = &X[(size_t)rA * F_IN + kgrp];

  f32x4 acc[8];
#pragma unroll
  for (int i = 0; i < 8; ++i) acc[i] = (f32x4){0.f, 0.f, 0.f, 0.f};

  float4 a0 = *(const float4*)(xp);
  float4 a1 = *(const float4*)(xp + 4);
  __syncthreads();

#pragma unroll
  for (int k0 = 0; k0 < F_IN; k0 += 32) {
    bf16x8 af;
    {
      const float av[8] = {a0.x, a0.y, a0.z, a0.w, a1.x, a1.y, a1.z, a1.w};
#pragma unroll
      for (int j = 0; j < 8; ++j) af[j] = (__bf16)av[j];
    }
    if (k0 + 32 < F_IN) {                       // prefetch next A chunk
      a0 = *(const float4*)(xp + k0 + 32);
      a1 = *(const float4*)(xp + k0 + 36);
    }
    const int kc = (k0 + kgrp) >> 3;
#pragma unroll
    for (int nf = 0; nf < 8; ++nf) {
      const int n = nf * 16 + l15;
      const s16x8 braw = *(const s16x8*)&Bs[n][(kc ^ (n & 7)) << 3];
      const bf16x8 bv = __builtin_bit_cast(bf16x8, braw);
      acc[nf] = __builtin_amdgcn_mfma_f32_16x16x32_bf16(af, bv, acc[nf], 0, 0, 0);
    }
  }
  // D: col = lane&15, row = (lane>>4)*4 + r
  const int rowD = blockIdx.x * 64 + wv_ * 16 + ((lane >> 4) << 2);
#pragma unroll
  for (int r = 0; r < 4; ++r) {
    if (rowD + r < M) {
      unsigned short* hp = &H[(size_t)(rowD + r) * F_HID + l15];
#pragma unroll
      for (int nf = 0; nf < 8; ++nf) hp[nf * 16] = f2bf(acc[nf][r]);
    }
  }
}

// ---------------- GEMM2 (MFMA): h2 = bf16((0.9*relu(agg1)+0.1) @ W2), (Mx128)@(128x64) ----------------
__global__ __launch_bounds__(256) void k_gemm2(const unsigned short* __restrict__ A1,
                                               const float* __restrict__ W2,
                                               unsigned short* __restrict__ H2, int M) {
  __shared__ unsigned short Bs[64][128];  // 16 KB
  const int tid = threadIdx.x;
#pragma unroll
  for (int r = 0; r < 8; ++r) {          // 2048 float4-groups: k=128 x ng=16
    const int idx = r * 256 + tid;
    const int k = idx & 127;
    const int ng = idx >> 7;
    const float4 w = *(const float4*)&W2[(size_t)k * F_OUT + ng * 4];
    const int kc = k >> 3, kb = k & 7;
    const float wv[4] = {w.x, w.y, w.z, w.w};
#pragma unroll
    for (int c = 0; c < 4; ++c) {
      const int n = ng * 4 + c;
      Bs[n][((kc ^ (n & 7)) << 3) | kb] = f2bf(wv[c]);
    }
  }
  const int lane = tid & 63;
  const int wv_ = tid >> 6;
  const int l15 = lane & 15;
  const int kgrp = (lane >> 4) << 3;
  const int rowA = blockIdx.x * 64 + wv_ * 16 + l15;
  const int rA = rowA < M ? rowA : M - 1;
  const unsigned short* ap = &A1[(size_t)rA * F_HID + kgrp];

  f32x4 acc[4];
#pragma unroll
  for (int i = 0; i < 4; ++i) acc[i] = (f32x4){0.f, 0.f, 0.f, 0.f};

  s16x8 raw = *(const s16x8*)(ap);
  __syncthreads();

#pragma unroll
  for (int k0 = 0; k0 < F_HID; k0 += 32) {
    bf16x8 af;
#pragma unroll
    for (int j = 0; j < 8; ++j) {
      float f = bf2f((unsigned short)raw[j]);
      f = 0.9f * fmaxf(f, 0.0f) + 0.1f;        // fused relu + CRF-mix
      af[j] = (__bf16)f;
    }
    if (k0 + 32 < F_HID) raw = *(const s16x8*)(ap + k0 + 32);
    const int kc = (k0 + kgrp) >> 3;
#pragma unroll
    for (int nf = 0; nf < 4; ++nf) {
      const int n = nf * 16 + l15;
      const s16x8 braw = *(const s16x8*)&Bs[n][(kc ^ (n & 7)) << 3];
      const bf16x8 bv = __builtin_bit_cast(bf16x8, braw);
      acc[nf] = __builtin_amdgcn_mfma_f32_16x16x32_bf16(af, bv, acc[nf], 0, 0, 0);
    }
  }
  const int rowD = blockIdx.x * 64 + wv_ * 16 + ((lane >> 4) << 2);
#pragma unroll
  for (int r = 0; r < 4; ++r) {
    if (rowD + r < M) {
      unsigned short* hp = &H2[(size_t)(rowD + r) * F_OUT + l15];
#pragma unroll
      for (int nf = 0; nf < 4; ++nf) hp[nf * 16] = f2bf(acc[nf][r]);
    }
  }
}

// ---------------- layer-1 gather: wave/node, lane owns 2 bf16 feats, f32 accum ----------------
__global__ __launch_bounds__(256) void k_gather1(const int* __restrict__ rowptr,
                                                 const int* __restrict__ csr_src,
                                                 const float* __restrict__ dinv,
                                                 const unsigned short* __restrict__ h0,
                                                 const float* __restrict__ b1,
                                                 unsigned short* __restrict__ agg1, int N) {
  const int node = (blockIdx.x << 2) + (threadIdx.x >> 6);
  if (node >= N) return;
  const int lane = threadIdx.x & 63;
  const int beg = rowptr[node];
  const int end = rowptr[node + 1];
  const float dv = dinv[node];
  const unsigned self = *(const unsigned*)&h0[(size_t)node * F_HID + lane * 2];
  const float2 bb = *(const float2*)&b1[lane * 2];
  float ax = dv * dv * bf2f((unsigned short)(self & 0xffff)) + bb.x;
  float ay = dv * dv * bf2f((unsigned short)(self >> 16)) + bb.y;
  int j = beg;
  for (; j + 3 < end; j += 4) {
    const int s0 = csr_src[j], s1 = csr_src[j + 1], s2 = csr_src[j + 2], s3 = csr_src[j + 3];
    const float w0 = dinv[s0] * dv, w1 = dinv[s1] * dv, w2 = dinv[s2] * dv, w3 = dinv[s3] * dv;
    const unsigned v0 = *(const unsigned*)&h0[(size_t)s0 * F_HID + lane * 2];
    const unsigned v1 = *(const unsigned*)&h0[(size_t)s1 * F_HID + lane * 2];
    const unsigned v2 = *(const unsigned*)&h0[(size_t)s2 * F_HID + lane * 2];
    const unsigned v3 = *(const unsigned*)&h0[(size_t)s3 * F_HID + lane * 2];
    ax += w0 * bf2f((unsigned short)(v0 & 0xffff)) + w1 * bf2f((unsigned short)(v1 & 0xffff))
        + w2 * bf2f((unsigned short)(v2 & 0xffff)) + w3 * bf2f((unsigned short)(v3 & 0xffff));
    ay += w0 * bf2f((unsigned short)(v0 >> 16)) + w1 * bf2f((unsigned short)(v1 >> 16))
        + w2 * bf2f((unsigned short)(v2 >> 16)) + w3 * bf2f((unsigned short)(v3 >> 16));
  }
  for (; j < end; ++j) {
    const int s = csr_src[j];
    const float w = dinv[s] * dv;
    const unsigned v = *(const unsigned*)&h0[(size_t)s * F_HID + lane * 2];
    ax += w * bf2f((unsigned short)(v & 0xffff));
    ay += w * bf2f((unsigned short)(v >> 16));
  }
  const unsigned packed = (unsigned)f2bf(ax) | ((unsigned)f2bf(ay) << 16);
  *(unsigned*)&agg1[(size_t)node * F_HID + lane * 2] = packed;
}

// ---------------- layer-2 gather + log_softmax: wave/node, lane owns 1 feat ----------------
__global__ __launch_bounds__(256) void k_gather2_lsm(const int* __restrict__ rowptr,
                                                     const int* __restrict__ csr_src,
                                                     const float* __restrict__ dinv,
                                                     const unsigned short* __restrict__ h2,
                                                     const float* __restrict__ b2,
                                                     float* __restrict__ outv, int N) {
  const int node = (blockIdx.x << 2) + (threadIdx.x >> 6);
  if (node >= N) return;
  const int lane = threadIdx.x & 63;
  const int beg = rowptr[node];
  const int end = rowptr[node + 1];
  const float dv = dinv[node];
  float acc = dv * dv * bf2f(h2[(size_t)node * F_OUT + lane]) + b2[lane];
  int j = beg;
  for (; j + 3 < end; j += 4) {
    const int s0 = csr_src[j], s1 = csr_src[j + 1], s2 = csr_src[j + 2], s3 = csr_src[j + 3];
    const float p0 = dinv[s0] * bf2f(h2[(size_t)s0 * F_OUT + lane]);
    const float p1 = dinv[s1] * bf2f(h2[(size_t)s1 * F_OUT + lane]);
    const float p2 = dinv[s2] * bf2f(h2[(size_t)s2 * F_OUT + lane]);
    const float p3 = dinv[s3] * bf2f(h2[(size_t)s3 * F_OUT + lane]);
    acc += dv * (p0 + p1 + p2 + p3);
  }
  for (; j < end; ++j) {
    const int s = csr_src[j];
    acc += dinv[s] * dv * bf2f(h2[(size_t)s * F_OUT + lane]);
  }
  float m = acc;
#pragma unroll
  for (int off = 32; off; off >>= 1) m = fmaxf(m, __shfl_xor(m, off));
  const float ex = expf(acc - m);
  float s = ex;
#pragma unroll
  for (int off = 32; off; off >>= 1) s += __shfl_xor(s, off);
  outv[(size_t)node * F_OUT + lane] = acc - m - logf(s);
}

// ---------------- launch ----------------
extern "C" void kernel_launch(void* const* d_in, const int* in_sizes, int n_in,
                              void* d_out, int out_size, void* d_ws, size_t ws_size,
                              hipStream_t stream) {
  const float* x  = (const float*)d_in[0];
  const int*   ei = (const int*)d_in[1];
  // d_in[2] = edge_weight: unused (CRF softmax over singleton groups == 1)
  const float* W1 = (const float*)d_in[3];
  const float* b1 = (const float*)d_in[4];
  const float* W2 = (const float*)d_in[5];
  const float* b2 = (const float*)d_in[6];

  const int N = in_sizes[0] / F_IN;
  const int E = in_sizes[1] / 2;
  const int* srcv = ei;
  const int* dstv = ei + E;
  const int B = (N + 1023) / 1024;

  float* ws = (float*)d_ws;
  const size_t Na = ((size_t)N + 256) & ~(size_t)255;
  const size_t Ea = ((size_t)E + 255) & ~(size_t)255;
  float* dinv    = ws;                         // N f32
  int*   deg     = (int*)(ws + Na);            // N
  int*   fill    = deg + Na;                   // N (contiguous with deg for one memset)
  int*   rowptr  = fill + Na;                  // N+1
  int*   chunkS  = rowptr + Na;                // <=128
  int*   chunkO  = chunkS + 128;
  int*   csr_src = chunkO + 128;               // E
  unsigned short* h0b   = (unsigned short*)(csr_src + Ea);   // N*128 bf16
  unsigned short* agg1b = h0b + (size_t)N * F_HID;           // N*128 bf16
  unsigned short* h2b   = agg1b + (size_t)N * F_HID;         // N*64 bf16
  float* outp = (float*)d_out;

  // ---- CSR build ----
  hipMemsetAsync(deg, 0, (Na + (size_t)N) * sizeof(int), stream);  // deg + fill
  k_count_deg<<<(E + 255) / 256, 256, 0, stream>>>(dstv, E, deg);
  k_dinv<<<(N + 255) / 256, 256, 0, stream>>>(deg, dinv, N);
  k_chunk_sum<<<B, 1024, 0, stream>>>(deg, chunkS, N);
  k_scan_off<<<1, 128, 0, stream>>>(chunkS, chunkO, B, rowptr, N, E);
  k_scan_apply<<<B, 1024, 0, stream>>>(deg, chunkO, rowptr, N);
  k_fill<<<(E + 255) / 256, 256, 0, stream>>>(srcv, dstv, rowptr, fill, csr_src, E);

  // ---- layer 1 ----
  k_gemm1<<<(N + 63) / 64, 256, 0, stream>>>(x, W1, h0b, N);
  k_gather1<<<(N + 3) / 4, 256, 0, stream>>>(rowptr, csr_src, dinv, h0b, b1, agg1b, N);

  // ---- layer 2 ----
  k_gemm2<<<(N + 63) / 64, 256, 0, stream>>>(agg1b, W2, h2b, N);
  k_gather2_lsm<<<(N + 3) / 4, 256, 0, stream>>>(rowptr, csr_src, dinv, h2b, b2, outp, N);
}